// Round 9
// baseline (952.221 us; speedup 1.0000x reference)
//
#include <hip/hip_runtime.h>
#include <math.h>

#define BB 16
#define CC 256
#define TT 4096
#define NA 1024
#define NB 3072
#define OC 512

#define NCH 4          // j-chunks for MFMA sim kernel (768 j each)
#define NPART (NCH*2)  // partials: chunk x wc-half (race-free per-wave writes)
#define DELTA 2e-4f    // margin below which a row falls back to exact fp32 argmax

typedef float f32x4 __attribute__((ext_vector_type(4)));
typedef short bf16x8 __attribute__((ext_vector_type(8)));

// ---------------- K1: per-token L2 norm over C ----------------
__global__ void k_norm(const float* __restrict__ x, float* __restrict__ norms) {
    int idx = blockIdx.x * 256 + threadIdx.x;   // b*TT + t
    int b = idx >> 12;
    int t = idx & 4095;
    const float* xp = x + (size_t)b * CC * TT + t;
    float s = 0.f;
#pragma unroll 8
    for (int c = 0; c < CC; ++c) {
        float v = xp[(size_t)c * TT];
        s = fmaf(v, v, s);
    }
    norms[idx] = sqrtf(s);
}

// ---------------- K2: transpose-pack normalized a/b tokens (fp32 only) ----------------
__global__ void k_pack(const float* __restrict__ x, const float* __restrict__ norms,
                       float* __restrict__ Ap, float* __restrict__ Bp) {
    __shared__ float tile[64][65];
    __shared__ float ns[64];
    int b = blockIdx.z, c0 = blockIdx.y * 64, t0 = blockIdx.x * 64;
    int tid = threadIdx.x;
#pragma unroll
    for (int rep = 0; rep < 16; ++rep) {
        int lin = rep * 256 + tid;
        int i = lin >> 6, j = lin & 63;
        tile[i][j] = x[((size_t)b * CC + c0 + i) * TT + t0 + j];
    }
    if (tid < 64) ns[tid] = norms[b * TT + t0 + tid];
    __syncthreads();
#pragma unroll
    for (int rep = 0; rep < 16; ++rep) {
        int lin = rep * 256 + tid;
        int j = lin >> 6, i = lin & 63;
        int t = t0 + j;
        float v = tile[i][j] / ns[j];
        if ((t & 3) == 0) {
            Ap[((size_t)b * NA + (t >> 2)) * CC + c0 + i] = v;
        } else {
            int g = t >> 2, r = t & 3;
            Bp[((size_t)b * NB + 3 * g + (r - 1)) * CC + c0 + i] = v;
        }
    }
}

// ---------------- K3: MFMA sim via in-register bf16 hi/lo split ----------------
__device__ inline void gl16f(const float* g, char* l) {
    __builtin_amdgcn_global_load_lds((const __attribute__((address_space(1))) void*)g,
                                     (__attribute__((address_space(3))) void*)l, 16, 0, 0);
}

__device__ inline void split8(float4 p0, float4 p1, bf16x8& hi, bf16x8& lo) {
    float f[8] = {p0.x, p0.y, p0.z, p0.w, p1.x, p1.y, p1.z, p1.w};
#pragma unroll
    for (int j = 0; j < 8; ++j) {
        uint u = __float_as_uint(f[j]);
        hi[j] = (short)(u >> 16);
        float hf = __uint_as_float(u & 0xffff0000u);
        lo[j] = (short)(__float_as_uint(f[j] - hf) >> 16);
    }
}

__global__ void __launch_bounds__(256, 2) k_sim(const float* __restrict__ Ap,
                                                const float* __restrict__ Bp,
                                                float* __restrict__ Pv1, int* __restrict__ Pi1,
                                                float* __restrict__ Pv2) {
    __shared__ __align__(16) char lds[65536];   // A-tile 32KB (128r x 64k fp32) | B-tile 32KB
    const int b = blockIdx.z;
    const int ch = blockIdx.y;
    const int i0 = blockIdx.x * 128;
    const int tid = threadIdx.x;
    const int l = tid & 63, wid = tid >> 6;
    const int wr = wid >> 1, wc = wid & 1;      // 2x2 wave grid, 64x64 per wave
    const int lr = l & 15, lk = l >> 4;
    const float* Abase = Ap + ((size_t)b * NA + i0) * CC;
    const float* Bbase = Bp + (size_t)b * NB * CC;

    float rv1[16], rv2[16];
    int ri1[16];
#pragma unroll
    for (int q = 0; q < 16; ++q) { rv1[q] = -1e30f; rv2[q] = -1e30f; ri1[q] = 0; }

    for (int jt = 0; jt < 6; ++jt) {
        const int j0 = ch * 768 + jt * 128;
        f32x4 acc[4][4];
#pragma unroll
        for (int mf = 0; mf < 4; ++mf)
#pragma unroll
            for (int nf = 0; nf < 4; ++nf) acc[mf][nf] = (f32x4){0.f, 0.f, 0.f, 0.f};

        for (int kt = 0; kt < 4; ++kt) {
            __syncthreads();
            // stage fp32 tiles; source pre-swizzled at 16B granularity: slot' = slot ^ (r&14)
#pragma unroll
            for (int s = 0; s < 8; ++s) {
                int off = s * 4096 + tid * 16;
                int r = off >> 8;
                int slot = (off >> 4) & 15;
                int srco = kt * 64 + ((slot ^ (r & 14)) << 2);
                gl16f(Abase + (size_t)r * CC + srco, lds + off);
                gl16f(Bbase + (size_t)(j0 + r) * CC + srco, lds + 32768 + off);
            }
            __syncthreads();
#pragma unroll
            for (int ks = 0; ks < 2; ++ks) {
                bf16x8 ahi[4], alo[4];
#pragma unroll
                for (int mf = 0; mf < 4; ++mf) {
                    int r = wr * 64 + mf * 16 + lr;
                    int sl = ((ks * 4 + lk) * 2) ^ (r & 14);
                    float4 p0 = *(const float4*)(lds + r * 256 + sl * 16);
                    float4 p1 = *(const float4*)(lds + r * 256 + sl * 16 + 16);
                    split8(p0, p1, ahi[mf], alo[mf]);
                }
#pragma unroll
                for (int nf = 0; nf < 4; ++nf) {
                    int r = wc * 64 + nf * 16 + lr;
                    int sl = ((ks * 4 + lk) * 2) ^ (r & 14);
                    float4 p0 = *(const float4*)(lds + 32768 + r * 256 + sl * 16);
                    float4 p1 = *(const float4*)(lds + 32768 + r * 256 + sl * 16 + 16);
                    bf16x8 bhi, blo;
                    split8(p0, p1, bhi, blo);
#pragma unroll
                    for (int mf = 0; mf < 4; ++mf) {
                        acc[mf][nf] = __builtin_amdgcn_mfma_f32_16x16x32_bf16(ahi[mf], blo, acc[mf][nf], 0, 0, 0);
                        acc[mf][nf] = __builtin_amdgcn_mfma_f32_16x16x32_bf16(alo[mf], bhi, acc[mf][nf], 0, 0, 0);
                        acc[mf][nf] = __builtin_amdgcn_mfma_f32_16x16x32_bf16(ahi[mf], bhi, acc[mf][nf], 0, 0, 0);
                    }
                }
            }
        }
        // per-row top2: D mapping col=lane&15, row=(lane>>4)*4+reg  [m89]
#pragma unroll
        for (int mf = 0; mf < 4; ++mf)
#pragma unroll
            for (int reg = 0; reg < 4; ++reg) {
                int q = mf * 4 + reg;
                float v1 = acc[mf][0][reg];
                int i1 = j0 + wc * 64 + lr;
                float v2 = -1e30f;
#pragma unroll
                for (int nf = 1; nf < 4; ++nf) {
                    float xv = acc[mf][nf][reg];
                    int xi = j0 + wc * 64 + nf * 16 + lr;
                    if (xv > v1) { v2 = v1; v1 = xv; i1 = xi; }
                    else v2 = fmaxf(v2, xv);
                }
#pragma unroll
                for (int d = 1; d < 16; d <<= 1) {
                    float ov1 = __shfl_xor(v1, d, 64);
                    int oi1 = __shfl_xor(i1, d, 64);
                    float ov2 = __shfl_xor(v2, d, 64);
                    bool take = (ov1 > v1) || (ov1 == v1 && oi1 < i1);
                    float bw = take ? v1 : ov1;
                    v2 = fmaxf(fmaxf(v2, ov2), bw);
                    if (take) { v1 = ov1; i1 = oi1; }
                }
                bool t2 = (v1 > rv1[q]);
                float bw2 = t2 ? rv1[q] : v1;
                rv2[q] = fmaxf(fmaxf(rv2[q], v2), bw2);
                if (t2) { rv1[q] = v1; ri1[q] = i1; }
            }
    }
    // race-free: each wave writes its own (chunk, wc-half) partial
    if (lr == 0) {
        int pch = ch * 2 + wc;
#pragma unroll
        for (int mf = 0; mf < 4; ++mf)
#pragma unroll
            for (int reg = 0; reg < 4; ++reg) {
                int row = i0 + wr * 64 + mf * 16 + lk * 4 + reg;
                size_t o = ((size_t)b * NPART + pch) * NA + row;
                int q = mf * 4 + reg;
                Pv1[o] = rv1[q]; Pi1[o] = ri1[q]; Pv2[o] = rv2[q];
            }
    }
}

// ---------------- K3b: merge partials -> sel + margin flag (index tie-break) ----------------
__global__ void k_reduce2(const float* __restrict__ Pv1, const int* __restrict__ Pi1,
                          const float* __restrict__ Pv2, int* __restrict__ sel,
                          int* __restrict__ flags) {
    int idx = blockIdx.x * 256 + threadIdx.x;   // b*NA + a
    int b = idx >> 10;
    int a = idx & 1023;
    float v1 = -1e30f, v2 = -1e30f;
    int i1 = 0x7fffffff;
#pragma unroll
    for (int pc = 0; pc < NPART; ++pc) {
        size_t o = ((size_t)b * NPART + pc) * NA + a;
        float nv1 = Pv1[o];
        int ni1 = Pi1[o];
        bool take = (nv1 > v1) || (nv1 == v1 && ni1 < i1);
        float bw = take ? v1 : nv1;
        v2 = fmaxf(fmaxf(v2, Pv2[o]), bw);
        if (take) { v1 = nv1; i1 = ni1; }
    }
    int g = i1 / 3, r = i1 - 3 * g;
    sel[idx] = 4 * g + r + 1;
    flags[idx] = (v1 - v2 < DELTA) ? 1 : 0;
}

// ---------------- K3c: exact fp32 re-argmax for flagged (low-margin) rows ----------------
__global__ void k_fallback(const float* __restrict__ Ap, const float* __restrict__ Bp,
                           const int* __restrict__ flags, int* __restrict__ sel) {
    int row = blockIdx.x;                 // b*NA + a
    if (!flags[row]) return;
    int b = row >> 10, a = row & 1023;
    __shared__ float arow[CC];
    int tt = threadIdx.x;                 // 64 threads = 1 wave
    const float* ar = Ap + ((size_t)b * NA + a) * CC;
    *(float4*)&arow[tt * 4] = *(const float4*)(ar + tt * 4);
    __syncthreads();
    float bv = -1e30f;
    int bi = 0;
    for (int j = tt; j < NB; j += 64) {
        const float* br = Bp + ((size_t)b * NB + j) * CC;
        float s = 0.f;
#pragma unroll
        for (int c = 0; c < CC; c += 4) {
            float4 bb = *(const float4*)(br + c);
            s = fmaf(arow[c], bb.x, s);
            s = fmaf(arow[c + 1], bb.y, s);
            s = fmaf(arow[c + 2], bb.z, s);
            s = fmaf(arow[c + 3], bb.w, s);
        }
        if (s > bv) { bv = s; bi = j; }   // per-thread ascending j, strict >
    }
#pragma unroll
    for (int d = 1; d < 64; d <<= 1) {
        float ov = __shfl_xor(bv, d, 64);
        int oi = __shfl_xor(bi, d, 64);
        if (ov > bv || (ov == bv && oi < bi)) { bv = ov; bi = oi; }
    }
    if (tt == 0) {
        int g = bi / 3, r = bi - 3 * g;
        sel[row] = 4 * g + r + 1;
    }
}

// ---------------- K4a: fuse (sim-merge + spatial-merge), write F[b][c][p] ----------------
__global__ void k_fuse(const float* __restrict__ x, const int* __restrict__ sel,
                       const float* __restrict__ fwraw, float* __restrict__ F) {
    int b = blockIdx.y;
    int p = blockIdx.x * 256 + threadIdx.x;
    float w0 = fminf(fmaxf(fwraw[0], 0.f), 6.f);
    float w1 = fminf(fmaxf(fwraw[1], 0.f), 6.f);
    float s = w0 + w1 + 1e-8f;
    float fw0 = w0 / s, fw1 = w1 / s;
    int lin = 4 * p;
    int col = lin & 63;
    int spa = (col == 0) ? lin + 1 : lin - 1;
    int ssim = sel[b * NA + p];
    const float* xb_ = x + (size_t)b * CC * TT;
    float* Fb = F + (size_t)b * CC * NA;
    for (int c = 0; c < CC; ++c) {
        const float* xr = xb_ + (size_t)c * TT;
        float xa = xr[lin], xs = xr[ssim], xp = xr[spa];
        float ms = (xa + xs) * 0.5f;
        float mp = (xa + xp) * 0.5f;
        Fb[(size_t)c * NA + p] = fw0 * ms + fw1 * mp;
    }
}

// ---------------- K4b: 1x1 conv GEMM + BN + SiLU ----------------
__global__ void __launch_bounds__(256) k_conv(const float* __restrict__ F, const float* __restrict__ W,
                                              const float* __restrict__ gamma, const float* __restrict__ beta,
                                              const float* __restrict__ mean, const float* __restrict__ var,
                                              float* __restrict__ out) {
    __shared__ float Ws[16][68];
    __shared__ float Fs[16][68];
    int b = blockIdx.z;
    int o0 = blockIdx.y * 64;
    int p0 = blockIdx.x * 64;
    int tid = threadIdx.x;
    int tr = tid >> 4, tc = tid & 15;
    int sr = tid >> 2, skb = (tid & 3) * 4;
    int fkk = tid >> 4, fj = (tid & 15) * 4;
    const float* Fb = F + (size_t)b * CC * NA;
    float acc[4][4];
#pragma unroll
    for (int u = 0; u < 4; ++u)
#pragma unroll
        for (int v = 0; v < 4; ++v) acc[u][v] = 0.f;

    for (int kt = 0; kt < CC / 16; ++kt) {
        __syncthreads();
        float4 w4 = *(const float4*)(W + (size_t)(o0 + sr) * CC + kt * 16 + skb);
        Ws[skb + 0][sr] = w4.x; Ws[skb + 1][sr] = w4.y;
        Ws[skb + 2][sr] = w4.z; Ws[skb + 3][sr] = w4.w;
        float4 f4 = *(const float4*)(Fb + (size_t)(kt * 16 + fkk) * NA + p0 + fj);
        *(float4*)&Fs[fkk][fj] = f4;
        __syncthreads();
#pragma unroll
        for (int kk = 0; kk < 16; ++kk) {
            float4 av = *(const float4*)&Ws[kk][tr * 4];
            float4 bv4 = *(const float4*)&Fs[kk][tc * 4];
            float a_[4] = {av.x, av.y, av.z, av.w};
            float b_[4] = {bv4.x, bv4.y, bv4.z, bv4.w};
#pragma unroll
            for (int u = 0; u < 4; ++u)
#pragma unroll
                for (int v = 0; v < 4; ++v)
                    acc[u][v] = fmaf(a_[u], b_[v], acc[u][v]);
        }
    }
#pragma unroll
    for (int u = 0; u < 4; ++u) {
        int o = o0 + tr * 4 + u;
        float sc = gamma[o] / sqrtf(var[o] + 1e-5f);
        float sh = fmaf(-mean[o], sc, beta[o]);
        float4 r;
        float* rp = &r.x;
#pragma unroll
        for (int v = 0; v < 4; ++v) {
            float y = fmaf(acc[u][v], sc, sh);
            rp[v] = y / (1.f + expf(-y));
        }
        *(float4*)(out + ((size_t)b * OC + o) * NA + p0 + tc * 4) = r;
    }
}

extern "C" void kernel_launch(void* const* d_in, const int* in_sizes, int n_in,
                              void* d_out, int out_size, void* d_ws, size_t ws_size,
                              hipStream_t stream) {
    const float* x      = (const float*)d_in[0];
    const float* conv_w = (const float*)d_in[1];
    const float* gamma  = (const float*)d_in[2];
    const float* beta   = (const float*)d_in[3];
    const float* mean   = (const float*)d_in[4];
    const float* var    = (const float*)d_in[5];
    const float* fw     = (const float*)d_in[6];
    float* out = (float*)d_out;

    float* ws    = (float*)d_ws;
    float* norms = ws;                                     // BB*TT f
    float* Ap    = norms + (size_t)BB * TT;                // BB*NA*CC f
    float* Bp    = Ap + (size_t)BB * NA * CC;              // BB*NB*CC f
    float* Pv1   = Bp + (size_t)BB * NB * CC;              // BB*NPART*NA f
    float* Pv2   = Pv1 + (size_t)BB * NPART * NA;          // BB*NPART*NA f
    int*   Pi1   = (int*)(Pv2 + (size_t)BB * NPART * NA);  // BB*NPART*NA i
    int*   sel   = Pi1 + (size_t)BB * NPART * NA;          // BB*NA i
    int*   flags = sel + (size_t)BB * NA;                  // BB*NA i
    float* F     = Ap;                                     // reuse Ap region after fallback

    k_norm<<<BB * TT / 256, 256, 0, stream>>>(x, norms);
    k_pack<<<dim3(TT / 64, CC / 64, BB), 256, 0, stream>>>(x, norms, Ap, Bp);
    k_sim<<<dim3(NA / 128, NCH, BB), 256, 0, stream>>>(Ap, Bp, Pv1, Pi1, Pv2);
    k_reduce2<<<BB * NA / 256, 256, 0, stream>>>(Pv1, Pi1, Pv2, sel, flags);
    k_fallback<<<BB * NA, 64, 0, stream>>>(Ap, Bp, flags, sel);
    k_fuse<<<dim3(NA / 256, BB), 256, 0, stream>>>(x, sel, fw, F);
    k_conv<<<dim3(NA / 64, OC / 64, BB), 256, 0, stream>>>(F, conv_w, gamma, beta, mean, var, out);
}

// Round 10
// 675.750 us; speedup vs baseline: 1.4091x; 1.4091x over previous
//
#include <hip/hip_runtime.h>
#include <math.h>

#define BB 16
#define CC 256
#define TT 4096
#define NA 1024
#define NB 3072
#define OC 512

#define NCH 4          // j-chunks for MFMA sim kernel (768 j each)
#define NPART (NCH*2)  // partials: chunk x wc-half (race-free per-wave writes)
#define DELTA 2e-4f    // margin below which a row falls back to exact fp32 argmax

typedef float f32x4 __attribute__((ext_vector_type(4)));
typedef short bf16x8 __attribute__((ext_vector_type(8)));

// ---------------- K1: per-token L2 norm over C ----------------
__global__ void k_norm(const float* __restrict__ x, float* __restrict__ norms) {
    int idx = blockIdx.x * 256 + threadIdx.x;   // b*TT + t
    int b = idx >> 12;
    int t = idx & 4095;
    const float* xp = x + (size_t)b * CC * TT + t;
    float s = 0.f;
#pragma unroll 8
    for (int c = 0; c < CC; ++c) {
        float v = xp[(size_t)c * TT];
        s = fmaf(v, v, s);
    }
    norms[idx] = sqrtf(s);
}

// ---------------- K2: transpose-pack normalized a/b tokens (fp32 only) ----------------
__global__ void k_pack(const float* __restrict__ x, const float* __restrict__ norms,
                       float* __restrict__ Ap, float* __restrict__ Bp) {
    __shared__ float tile[64][65];
    __shared__ float ns[64];
    int b = blockIdx.z, c0 = blockIdx.y * 64, t0 = blockIdx.x * 64;
    int tid = threadIdx.x;
#pragma unroll
    for (int rep = 0; rep < 16; ++rep) {
        int lin = rep * 256 + tid;
        int i = lin >> 6, j = lin & 63;
        tile[i][j] = x[((size_t)b * CC + c0 + i) * TT + t0 + j];
    }
    if (tid < 64) ns[tid] = norms[b * TT + t0 + tid];
    __syncthreads();
#pragma unroll
    for (int rep = 0; rep < 16; ++rep) {
        int lin = rep * 256 + tid;
        int j = lin >> 6, i = lin & 63;
        int t = t0 + j;
        float v = tile[i][j] / ns[j];
        if ((t & 3) == 0) {
            Ap[((size_t)b * NA + (t >> 2)) * CC + c0 + i] = v;
        } else {
            int g = t >> 2, r = t & 3;
            Bp[((size_t)b * NB + 3 * g + (r - 1)) * CC + c0 + i] = v;
        }
    }
}

// ---------------- K3: MFMA sim via in-register bf16 hi/lo split ----------------
__device__ inline void gl16f(const float* g, char* l) {
    __builtin_amdgcn_global_load_lds((const __attribute__((address_space(1))) void*)g,
                                     (__attribute__((address_space(3))) void*)l, 16, 0, 0);
}

__device__ inline void split8(float4 p0, float4 p1, bf16x8& hi, bf16x8& lo) {
    float f[8] = {p0.x, p0.y, p0.z, p0.w, p1.x, p1.y, p1.z, p1.w};
#pragma unroll
    for (int j = 0; j < 8; ++j) {
        uint u = __float_as_uint(f[j]);
        hi[j] = (short)(u >> 16);
        float hf = __uint_as_float(u & 0xffff0000u);
        lo[j] = (short)(__float_as_uint(f[j] - hf) >> 16);
    }
}

__global__ void __launch_bounds__(256, 2) k_sim(const float* __restrict__ Ap,
                                                const float* __restrict__ Bp,
                                                float* __restrict__ Pv1, int* __restrict__ Pi1,
                                                float* __restrict__ Pv2) {
    __shared__ __align__(16) char lds[65536];   // A-tile 32KB (128r x 64k fp32) | B-tile 32KB
    const int b = blockIdx.z;
    const int ch = blockIdx.y;
    const int i0 = blockIdx.x * 128;
    const int tid = threadIdx.x;
    const int l = tid & 63, wid = tid >> 6;
    const int wr = wid >> 1, wc = wid & 1;      // 2x2 wave grid, 64x64 per wave
    const int lr = l & 15, lk = l >> 4;
    const float* Abase = Ap + ((size_t)b * NA + i0) * CC;
    const float* Bbase = Bp + (size_t)b * NB * CC;

    float rv1[16], rv2[16];
    int ri1[16];
#pragma unroll
    for (int q = 0; q < 16; ++q) { rv1[q] = -1e30f; rv2[q] = -1e30f; ri1[q] = 0; }

    for (int jt = 0; jt < 6; ++jt) {
        const int j0 = ch * 768 + jt * 128;
        f32x4 acc[4][4];
#pragma unroll
        for (int mf = 0; mf < 4; ++mf)
#pragma unroll
            for (int nf = 0; nf < 4; ++nf) acc[mf][nf] = (f32x4){0.f, 0.f, 0.f, 0.f};

        for (int kt = 0; kt < 4; ++kt) {
            __syncthreads();
            // stage fp32 tiles; source pre-swizzled at 16B granularity: slot' = slot ^ (r&14)
#pragma unroll
            for (int s = 0; s < 8; ++s) {
                int off = s * 4096 + tid * 16;
                int r = off >> 8;
                int slot = (off >> 4) & 15;
                int srco = kt * 64 + ((slot ^ (r & 14)) << 2);
                gl16f(Abase + (size_t)r * CC + srco, lds + off);
                gl16f(Bbase + (size_t)(j0 + r) * CC + srco, lds + 32768 + off);
            }
            __syncthreads();
#pragma unroll
            for (int ks = 0; ks < 2; ++ks) {
                bf16x8 ahi[4], alo[4];
#pragma unroll
                for (int mf = 0; mf < 4; ++mf) {
                    int r = wr * 64 + mf * 16 + lr;
                    int sl = ((ks * 4 + lk) * 2) ^ (r & 14);
                    float4 p0 = *(const float4*)(lds + r * 256 + sl * 16);
                    float4 p1 = *(const float4*)(lds + r * 256 + sl * 16 + 16);
                    split8(p0, p1, ahi[mf], alo[mf]);
                }
#pragma unroll
                for (int nf = 0; nf < 4; ++nf) {
                    int r = wc * 64 + nf * 16 + lr;
                    int sl = ((ks * 4 + lk) * 2) ^ (r & 14);
                    float4 p0 = *(const float4*)(lds + 32768 + r * 256 + sl * 16);
                    float4 p1 = *(const float4*)(lds + 32768 + r * 256 + sl * 16 + 16);
                    bf16x8 bhi, blo;
                    split8(p0, p1, bhi, blo);
#pragma unroll
                    for (int mf = 0; mf < 4; ++mf) {
                        acc[mf][nf] = __builtin_amdgcn_mfma_f32_16x16x32_bf16(ahi[mf], blo, acc[mf][nf], 0, 0, 0);
                        acc[mf][nf] = __builtin_amdgcn_mfma_f32_16x16x32_bf16(alo[mf], bhi, acc[mf][nf], 0, 0, 0);
                        acc[mf][nf] = __builtin_amdgcn_mfma_f32_16x16x32_bf16(ahi[mf], bhi, acc[mf][nf], 0, 0, 0);
                    }
                }
            }
        }
        // per-row top2: D mapping col=lane&15, row=(lane>>4)*4+reg  [m89]
#pragma unroll
        for (int mf = 0; mf < 4; ++mf)
#pragma unroll
            for (int reg = 0; reg < 4; ++reg) {
                int q = mf * 4 + reg;
                float v1 = acc[mf][0][reg];
                int i1 = j0 + wc * 64 + lr;
                float v2 = -1e30f;
#pragma unroll
                for (int nf = 1; nf < 4; ++nf) {
                    float xv = acc[mf][nf][reg];
                    int xi = j0 + wc * 64 + nf * 16 + lr;
                    if (xv > v1) { v2 = v1; v1 = xv; i1 = xi; }
                    else v2 = fmaxf(v2, xv);
                }
#pragma unroll
                for (int d = 1; d < 16; d <<= 1) {
                    float ov1 = __shfl_xor(v1, d, 64);
                    int oi1 = __shfl_xor(i1, d, 64);
                    float ov2 = __shfl_xor(v2, d, 64);
                    bool take = (ov1 > v1) || (ov1 == v1 && oi1 < i1);
                    float bw = take ? v1 : ov1;
                    v2 = fmaxf(fmaxf(v2, ov2), bw);
                    if (take) { v1 = ov1; i1 = oi1; }
                }
                bool t2 = (v1 > rv1[q]);
                float bw2 = t2 ? rv1[q] : v1;
                rv2[q] = fmaxf(fmaxf(rv2[q], v2), bw2);
                if (t2) { rv1[q] = v1; ri1[q] = i1; }
            }
    }
    // race-free: each wave writes its own (chunk, wc-half) partial
    if (lr == 0) {
        int pch = ch * 2 + wc;
#pragma unroll
        for (int mf = 0; mf < 4; ++mf)
#pragma unroll
            for (int reg = 0; reg < 4; ++reg) {
                int row = i0 + wr * 64 + mf * 16 + lk * 4 + reg;
                size_t o = ((size_t)b * NPART + pch) * NA + row;
                int q = mf * 4 + reg;
                Pv1[o] = rv1[q]; Pi1[o] = ri1[q]; Pv2[o] = rv2[q];
            }
    }
}

// ---------------- K3b: merge partials -> sel + margin flag (index tie-break) ----------------
__global__ void k_reduce2(const float* __restrict__ Pv1, const int* __restrict__ Pi1,
                          const float* __restrict__ Pv2, int* __restrict__ sel,
                          int* __restrict__ flags) {
    int idx = blockIdx.x * 256 + threadIdx.x;   // b*NA + a
    int b = idx >> 10;
    int a = idx & 1023;
    float v1 = -1e30f, v2 = -1e30f;
    int i1 = 0x7fffffff;
#pragma unroll
    for (int pc = 0; pc < NPART; ++pc) {
        size_t o = ((size_t)b * NPART + pc) * NA + a;
        float nv1 = Pv1[o];
        int ni1 = Pi1[o];
        bool take = (nv1 > v1) || (nv1 == v1 && ni1 < i1);
        float bw = take ? v1 : nv1;
        v2 = fmaxf(fmaxf(v2, Pv2[o]), bw);
        if (take) { v1 = nv1; i1 = ni1; }
    }
    int g = i1 / 3, r = i1 - 3 * g;
    sel[idx] = 4 * g + r + 1;
    flags[idx] = (v1 - v2 < DELTA) ? 1 : 0;
}

// ---------------- K3c: exact fp32 re-argmax for flagged rows (coalesced) ----------------
// 4 waves/row; wave w owns j = w, w+4, ... (ascending per wave). Per j the 64 lanes
// read Bp[j][lane*4..+3] (one contiguous 1KB wave transaction), fma vs lane's arow
// quad, then 6-step shfl_xor sum. Cross-wave merge with index tie-break.
__global__ void k_fallback(const float* __restrict__ Ap, const float* __restrict__ Bp,
                           const int* __restrict__ flags, int* __restrict__ sel) {
    int row = blockIdx.x;                 // b*NA + a
    if (!flags[row]) return;
    int b = row >> 10, a = row & 1023;
    __shared__ float arow[CC];
    __shared__ float wv[4];
    __shared__ int wi[4];
    int tid = threadIdx.x;                // 256 threads = 4 waves
    int l = tid & 63, w = tid >> 6;
    if (tid < 64) *(float4*)&arow[tid * 4] = *(const float4*)(Ap + ((size_t)b * NA + a) * CC + tid * 4);
    __syncthreads();
    float4 av = *(const float4*)&arow[l * 4];
    const float* Bb = Bp + (size_t)b * NB * CC + l * 4;
    float bv = -1e30f;
    int bi = 0;
    for (int j = w; j < NB; j += 4) {
        float4 bb = *(const float4*)(Bb + (size_t)j * CC);
        float s = fmaf(av.w, bb.w, fmaf(av.z, bb.z, fmaf(av.y, bb.y, av.x * bb.x)));
#pragma unroll
        for (int d = 1; d < 64; d <<= 1) s += __shfl_xor(s, d, 64);
        if (s > bv) { bv = s; bi = j; }   // ascending j per wave, strict >
    }
    if (l == 0) { wv[w] = bv; wi[w] = bi; }
    __syncthreads();
    if (tid == 0) {
        float v = wv[0]; int i = wi[0];
#pragma unroll
        for (int q = 1; q < 4; ++q) {
            if (wv[q] > v || (wv[q] == v && wi[q] < i)) { v = wv[q]; i = wi[q]; }
        }
        int g = i / 3, r = i - 3 * g;
        sel[row] = 4 * g + r + 1;
    }
}

// ---------------- K4a: fuse (sim-merge + spatial-merge), write F[b][c][p] ----------------
__global__ void k_fuse(const float* __restrict__ x, const int* __restrict__ sel,
                       const float* __restrict__ fwraw, float* __restrict__ F) {
    int b = blockIdx.y;
    int p = blockIdx.x * 256 + threadIdx.x;
    float w0 = fminf(fmaxf(fwraw[0], 0.f), 6.f);
    float w1 = fminf(fmaxf(fwraw[1], 0.f), 6.f);
    float s = w0 + w1 + 1e-8f;
    float fw0 = w0 / s, fw1 = w1 / s;
    int lin = 4 * p;
    int col = lin & 63;
    int spa = (col == 0) ? lin + 1 : lin - 1;
    int ssim = sel[b * NA + p];
    const float* xb_ = x + (size_t)b * CC * TT;
    float* Fb = F + (size_t)b * CC * NA;
    for (int c = 0; c < CC; ++c) {
        const float* xr = xb_ + (size_t)c * TT;
        float xa = xr[lin], xs = xr[ssim], xp = xr[spa];
        float ms = (xa + xs) * 0.5f;
        float mp = (xa + xp) * 0.5f;
        Fb[(size_t)c * NA + p] = fw0 * ms + fw1 * mp;
    }
}

// ---------------- K4b: 1x1 conv GEMM + BN + SiLU ----------------
__global__ void __launch_bounds__(256) k_conv(const float* __restrict__ F, const float* __restrict__ W,
                                              const float* __restrict__ gamma, const float* __restrict__ beta,
                                              const float* __restrict__ mean, const float* __restrict__ var,
                                              float* __restrict__ out) {
    __shared__ float Ws[16][68];
    __shared__ float Fs[16][68];
    int b = blockIdx.z;
    int o0 = blockIdx.y * 64;
    int p0 = blockIdx.x * 64;
    int tid = threadIdx.x;
    int tr = tid >> 4, tc = tid & 15;
    int sr = tid >> 2, skb = (tid & 3) * 4;
    int fkk = tid >> 4, fj = (tid & 15) * 4;
    const float* Fb = F + (size_t)b * CC * NA;
    float acc[4][4];
#pragma unroll
    for (int u = 0; u < 4; ++u)
#pragma unroll
        for (int v = 0; v < 4; ++v) acc[u][v] = 0.f;

    for (int kt = 0; kt < CC / 16; ++kt) {
        __syncthreads();
        float4 w4 = *(const float4*)(W + (size_t)(o0 + sr) * CC + kt * 16 + skb);
        Ws[skb + 0][sr] = w4.x; Ws[skb + 1][sr] = w4.y;
        Ws[skb + 2][sr] = w4.z; Ws[skb + 3][sr] = w4.w;
        float4 f4 = *(const float4*)(Fb + (size_t)(kt * 16 + fkk) * NA + p0 + fj);
        *(float4*)&Fs[fkk][fj] = f4;
        __syncthreads();
#pragma unroll
        for (int kk = 0; kk < 16; ++kk) {
            float4 av = *(const float4*)&Ws[kk][tr * 4];
            float4 bv4 = *(const float4*)&Fs[kk][tc * 4];
            float a_[4] = {av.x, av.y, av.z, av.w};
            float b_[4] = {bv4.x, bv4.y, bv4.z, bv4.w};
#pragma unroll
            for (int u = 0; u < 4; ++u)
#pragma unroll
                for (int v = 0; v < 4; ++v)
                    acc[u][v] = fmaf(a_[u], b_[v], acc[u][v]);
        }
    }
#pragma unroll
    for (int u = 0; u < 4; ++u) {
        int o = o0 + tr * 4 + u;
        float sc = gamma[o] / sqrtf(var[o] + 1e-5f);
        float sh = fmaf(-mean[o], sc, beta[o]);
        float4 r;
        float* rp = &r.x;
#pragma unroll
        for (int v = 0; v < 4; ++v) {
            float y = fmaf(acc[u][v], sc, sh);
            rp[v] = y / (1.f + expf(-y));
        }
        *(float4*)(out + ((size_t)b * OC + o) * NA + p0 + tc * 4) = r;
    }
}

extern "C" void kernel_launch(void* const* d_in, const int* in_sizes, int n_in,
                              void* d_out, int out_size, void* d_ws, size_t ws_size,
                              hipStream_t stream) {
    const float* x      = (const float*)d_in[0];
    const float* conv_w = (const float*)d_in[1];
    const float* gamma  = (const float*)d_in[2];
    const float* beta   = (const float*)d_in[3];
    const float* mean   = (const float*)d_in[4];
    const float* var    = (const float*)d_in[5];
    const float* fw     = (const float*)d_in[6];
    float* out = (float*)d_out;

    float* ws    = (float*)d_ws;
    float* norms = ws;                                     // BB*TT f
    float* Ap    = norms + (size_t)BB * TT;                // BB*NA*CC f
    float* Bp    = Ap + (size_t)BB * NA * CC;              // BB*NB*CC f
    float* Pv1   = Bp + (size_t)BB * NB * CC;              // BB*NPART*NA f
    float* Pv2   = Pv1 + (size_t)BB * NPART * NA;          // BB*NPART*NA f
    int*   Pi1   = (int*)(Pv2 + (size_t)BB * NPART * NA);  // BB*NPART*NA i
    int*   sel   = Pi1 + (size_t)BB * NPART * NA;          // BB*NA i
    int*   flags = sel + (size_t)BB * NA;                  // BB*NA i
    float* F     = Ap;                                     // reuse Ap region after fallback

    k_norm<<<BB * TT / 256, 256, 0, stream>>>(x, norms);
    k_pack<<<dim3(TT / 64, CC / 64, BB), 256, 0, stream>>>(x, norms, Ap, Bp);
    k_sim<<<dim3(NA / 128, NCH, BB), 256, 0, stream>>>(Ap, Bp, Pv1, Pi1, Pv2);
    k_reduce2<<<BB * NA / 256, 256, 0, stream>>>(Pv1, Pi1, Pv2, sel, flags);
    k_fallback<<<BB * NA, 256, 0, stream>>>(Ap, Bp, flags, sel);
    k_fuse<<<dim3(NA / 256, BB), 256, 0, stream>>>(x, sel, fw, F);
    k_conv<<<dim3(NA / 64, OC / 64, BB), 256, 0, stream>>>(F, conv_w, gamma, beta, mean, var, out);
}

// Round 11
// 475.565 us; speedup vs baseline: 2.0023x; 1.4209x over previous
//
#include <hip/hip_runtime.h>
#include <math.h>

#define BB 16
#define CC 256
#define TT 4096
#define NA 1024
#define NB 3072
#define OC 512

#define NCH 4          // j-chunks for MFMA sim kernel (768 j each)
#define NPART (NCH*2)  // partials: chunk x wc-half (race-free per-wave writes)
#define DELTA 2e-4f    // margin below which a row falls back to exact fp32 argmax

typedef float f32x4 __attribute__((ext_vector_type(4)));
typedef short bf16x8 __attribute__((ext_vector_type(8)));

// ---------------- K1: per-token L2 norm over C ----------------
__global__ void k_norm(const float* __restrict__ x, float* __restrict__ norms) {
    int idx = blockIdx.x * 256 + threadIdx.x;   // b*TT + t
    int b = idx >> 12;
    int t = idx & 4095;
    const float* xp = x + (size_t)b * CC * TT + t;
    float s = 0.f;
#pragma unroll 8
    for (int c = 0; c < CC; ++c) {
        float v = xp[(size_t)c * TT];
        s = fmaf(v, v, s);
    }
    norms[idx] = sqrtf(s);
}

// ---------------- K2: transpose-pack normalized a/b tokens (fp32 only) ----------------
__global__ void k_pack(const float* __restrict__ x, const float* __restrict__ norms,
                       float* __restrict__ Ap, float* __restrict__ Bp) {
    __shared__ float tile[64][65];
    __shared__ float ns[64];
    int b = blockIdx.z, c0 = blockIdx.y * 64, t0 = blockIdx.x * 64;
    int tid = threadIdx.x;
#pragma unroll
    for (int rep = 0; rep < 16; ++rep) {
        int lin = rep * 256 + tid;
        int i = lin >> 6, j = lin & 63;
        tile[i][j] = x[((size_t)b * CC + c0 + i) * TT + t0 + j];
    }
    if (tid < 64) ns[tid] = norms[b * TT + t0 + tid];
    __syncthreads();
#pragma unroll
    for (int rep = 0; rep < 16; ++rep) {
        int lin = rep * 256 + tid;
        int j = lin >> 6, i = lin & 63;
        int t = t0 + j;
        float v = tile[i][j] / ns[j];
        if ((t & 3) == 0) {
            Ap[((size_t)b * NA + (t >> 2)) * CC + c0 + i] = v;
        } else {
            int g = t >> 2, r = t & 3;
            Bp[((size_t)b * NB + 3 * g + (r - 1)) * CC + c0 + i] = v;
        }
    }
}

// ---------------- K3: MFMA sim via in-register bf16 hi/lo split ----------------
__device__ inline void gl16f(const float* g, char* l) {
    __builtin_amdgcn_global_load_lds((const __attribute__((address_space(1))) void*)g,
                                     (__attribute__((address_space(3))) void*)l, 16, 0, 0);
}

__device__ inline void split8(float4 p0, float4 p1, bf16x8& hi, bf16x8& lo) {
    float f[8] = {p0.x, p0.y, p0.z, p0.w, p1.x, p1.y, p1.z, p1.w};
#pragma unroll
    for (int j = 0; j < 8; ++j) {
        uint u = __float_as_uint(f[j]);
        hi[j] = (short)(u >> 16);
        float hf = __uint_as_float(u & 0xffff0000u);
        lo[j] = (short)(__float_as_uint(f[j] - hf) >> 16);
    }
}

__global__ void __launch_bounds__(256, 2) k_sim(const float* __restrict__ Ap,
                                                const float* __restrict__ Bp,
                                                float* __restrict__ Pv1, int* __restrict__ Pi1,
                                                float* __restrict__ Pv2) {
    __shared__ __align__(16) char lds[65536];   // A-tile 32KB (128r x 64k fp32) | B-tile 32KB
    const int b = blockIdx.z;
    const int ch = blockIdx.y;
    const int i0 = blockIdx.x * 128;
    const int tid = threadIdx.x;
    const int l = tid & 63, wid = tid >> 6;
    const int wr = wid >> 1, wc = wid & 1;      // 2x2 wave grid, 64x64 per wave
    const int lr = l & 15, lk = l >> 4;
    const float* Abase = Ap + ((size_t)b * NA + i0) * CC;
    const float* Bbase = Bp + (size_t)b * NB * CC;

    float rv1[16], rv2[16];
    int ri1[16];
#pragma unroll
    for (int q = 0; q < 16; ++q) { rv1[q] = -1e30f; rv2[q] = -1e30f; ri1[q] = 0; }

    for (int jt = 0; jt < 6; ++jt) {
        const int j0 = ch * 768 + jt * 128;
        f32x4 acc[4][4];
#pragma unroll
        for (int mf = 0; mf < 4; ++mf)
#pragma unroll
            for (int nf = 0; nf < 4; ++nf) acc[mf][nf] = (f32x4){0.f, 0.f, 0.f, 0.f};

        for (int kt = 0; kt < 4; ++kt) {
            __syncthreads();
            // stage fp32 tiles; source pre-swizzled at 16B granularity: slot' = slot ^ (r&14)
#pragma unroll
            for (int s = 0; s < 8; ++s) {
                int off = s * 4096 + tid * 16;
                int r = off >> 8;
                int slot = (off >> 4) & 15;
                int srco = kt * 64 + ((slot ^ (r & 14)) << 2);
                gl16f(Abase + (size_t)r * CC + srco, lds + off);
                gl16f(Bbase + (size_t)(j0 + r) * CC + srco, lds + 32768 + off);
            }
            __syncthreads();
#pragma unroll
            for (int ks = 0; ks < 2; ++ks) {
                bf16x8 ahi[4], alo[4];
#pragma unroll
                for (int mf = 0; mf < 4; ++mf) {
                    int r = wr * 64 + mf * 16 + lr;
                    int sl = ((ks * 4 + lk) * 2) ^ (r & 14);
                    float4 p0 = *(const float4*)(lds + r * 256 + sl * 16);
                    float4 p1 = *(const float4*)(lds + r * 256 + sl * 16 + 16);
                    split8(p0, p1, ahi[mf], alo[mf]);
                }
#pragma unroll
                for (int nf = 0; nf < 4; ++nf) {
                    int r = wc * 64 + nf * 16 + lr;
                    int sl = ((ks * 4 + lk) * 2) ^ (r & 14);
                    float4 p0 = *(const float4*)(lds + 32768 + r * 256 + sl * 16);
                    float4 p1 = *(const float4*)(lds + 32768 + r * 256 + sl * 16 + 16);
                    bf16x8 bhi, blo;
                    split8(p0, p1, bhi, blo);
#pragma unroll
                    for (int mf = 0; mf < 4; ++mf) {
                        acc[mf][nf] = __builtin_amdgcn_mfma_f32_16x16x32_bf16(ahi[mf], blo, acc[mf][nf], 0, 0, 0);
                        acc[mf][nf] = __builtin_amdgcn_mfma_f32_16x16x32_bf16(alo[mf], bhi, acc[mf][nf], 0, 0, 0);
                        acc[mf][nf] = __builtin_amdgcn_mfma_f32_16x16x32_bf16(ahi[mf], bhi, acc[mf][nf], 0, 0, 0);
                    }
                }
            }
        }
        // per-row top2: D mapping col=lane&15, row=(lane>>4)*4+reg  [m89]
#pragma unroll
        for (int mf = 0; mf < 4; ++mf)
#pragma unroll
            for (int reg = 0; reg < 4; ++reg) {
                int q = mf * 4 + reg;
                float v1 = acc[mf][0][reg];
                int i1 = j0 + wc * 64 + lr;
                float v2 = -1e30f;
#pragma unroll
                for (int nf = 1; nf < 4; ++nf) {
                    float xv = acc[mf][nf][reg];
                    int xi = j0 + wc * 64 + nf * 16 + lr;
                    if (xv > v1) { v2 = v1; v1 = xv; i1 = xi; }
                    else v2 = fmaxf(v2, xv);
                }
#pragma unroll
                for (int d = 1; d < 16; d <<= 1) {
                    float ov1 = __shfl_xor(v1, d, 64);
                    int oi1 = __shfl_xor(i1, d, 64);
                    float ov2 = __shfl_xor(v2, d, 64);
                    bool take = (ov1 > v1) || (ov1 == v1 && oi1 < i1);
                    float bw = take ? v1 : ov1;
                    v2 = fmaxf(fmaxf(v2, ov2), bw);
                    if (take) { v1 = ov1; i1 = oi1; }
                }
                bool t2 = (v1 > rv1[q]);
                float bw2 = t2 ? rv1[q] : v1;
                rv2[q] = fmaxf(fmaxf(rv2[q], v2), bw2);
                if (t2) { rv1[q] = v1; ri1[q] = i1; }
            }
    }
    // race-free: each wave writes its own (chunk, wc-half) partial
    if (lr == 0) {
        int pch = ch * 2 + wc;
#pragma unroll
        for (int mf = 0; mf < 4; ++mf)
#pragma unroll
            for (int reg = 0; reg < 4; ++reg) {
                int row = i0 + wr * 64 + mf * 16 + lk * 4 + reg;
                size_t o = ((size_t)b * NPART + pch) * NA + row;
                int q = mf * 4 + reg;
                Pv1[o] = rv1[q]; Pi1[o] = ri1[q]; Pv2[o] = rv2[q];
            }
    }
}

// ---------------- K3b: merge partials -> sel + margin flag (index tie-break) ----------------
__global__ void k_reduce2(const float* __restrict__ Pv1, const int* __restrict__ Pi1,
                          const float* __restrict__ Pv2, int* __restrict__ sel,
                          int* __restrict__ flags) {
    int idx = blockIdx.x * 256 + threadIdx.x;   // b*NA + a
    int b = idx >> 10;
    int a = idx & 1023;
    float v1 = -1e30f, v2 = -1e30f;
    int i1 = 0x7fffffff;
#pragma unroll
    for (int pc = 0; pc < NPART; ++pc) {
        size_t o = ((size_t)b * NPART + pc) * NA + a;
        float nv1 = Pv1[o];
        int ni1 = Pi1[o];
        bool take = (nv1 > v1) || (nv1 == v1 && ni1 < i1);
        float bw = take ? v1 : nv1;
        v2 = fmaxf(fmaxf(v2, Pv2[o]), bw);
        if (take) { v1 = nv1; i1 = ni1; }
    }
    int g = i1 / 3, r = i1 - 3 * g;
    sel[idx] = 4 * g + r + 1;
    flags[idx] = (v1 - v2 < DELTA) ? 1 : 0;
}

// ---------------- K3c: exact fp32 re-argmax for flagged rows ----------------
// 8 waves/row; wave w owns 8-row groups jb = 8w + 64k. Per group: 8 independent
// coalesced 1KB loads + 8 dot-partials, then 6 butterfly steps x 8 interleaved
// chains (ILP hides DS latency). Slot/wave merges: (v >, tie -> smaller j) ==
// numpy first-occurrence.
__global__ void k_fallback(const float* __restrict__ Ap, const float* __restrict__ Bp,
                           const int* __restrict__ flags, int* __restrict__ sel) {
    int row = blockIdx.x;                 // b*NA + a
    if (!flags[row]) return;
    int b = row >> 10, a = row & 1023;
    __shared__ float arow[CC];
    __shared__ float wv[8];
    __shared__ int wi[8];
    int tid = threadIdx.x;                // 512 threads = 8 waves
    int l = tid & 63, w = tid >> 6;
    if (tid < 64) *(float4*)&arow[tid * 4] = *(const float4*)(Ap + ((size_t)b * NA + a) * CC + tid * 4);
    __syncthreads();
    float4 av = *(const float4*)&arow[l * 4];
    const float* Bb = Bp + (size_t)b * NB * CC + l * 4;
    float bv[8];
    int bi[8];
#pragma unroll
    for (int s = 0; s < 8; ++s) { bv[s] = -1e30f; bi[s] = 0; }
    for (int jb = w * 8; jb < NB; jb += 64) {
        float s8[8];
#pragma unroll
        for (int s = 0; s < 8; ++s) {
            float4 bb = *(const float4*)(Bb + (size_t)(jb + s) * CC);
            s8[s] = fmaf(av.w, bb.w, fmaf(av.z, bb.z, fmaf(av.y, bb.y, av.x * bb.x)));
        }
#pragma unroll
        for (int d = 1; d < 64; d <<= 1) {
#pragma unroll
            for (int s = 0; s < 8; ++s) s8[s] += __shfl_xor(s8[s], d, 64);
        }
#pragma unroll
        for (int s = 0; s < 8; ++s)
            if (s8[s] > bv[s]) { bv[s] = s8[s]; bi[s] = jb + s; }   // ascending per slot
    }
    float v = bv[0];
    int i = bi[0];
#pragma unroll
    for (int s = 1; s < 8; ++s)
        if (bv[s] > v || (bv[s] == v && bi[s] < i)) { v = bv[s]; i = bi[s]; }
    if (l == 0) { wv[w] = v; wi[w] = i; }
    __syncthreads();
    if (tid == 0) {
        float vm = wv[0]; int im = wi[0];
#pragma unroll
        for (int q = 1; q < 8; ++q)
            if (wv[q] > vm || (wv[q] == vm && wi[q] < im)) { vm = wv[q]; im = wi[q]; }
        int g = im / 3, r = im - 3 * g;
        sel[row] = 4 * g + r + 1;
    }
}

// ---------------- K4a: fuse (sim-merge + spatial-merge), write F[b][c][p] ----------------
__global__ void k_fuse(const float* __restrict__ x, const int* __restrict__ sel,
                       const float* __restrict__ fwraw, float* __restrict__ F) {
    int b = blockIdx.y;
    int p = blockIdx.x * 256 + threadIdx.x;
    float w0 = fminf(fmaxf(fwraw[0], 0.f), 6.f);
    float w1 = fminf(fmaxf(fwraw[1], 0.f), 6.f);
    float s = w0 + w1 + 1e-8f;
    float fw0 = w0 / s, fw1 = w1 / s;
    int lin = 4 * p;
    int col = lin & 63;
    int spa = (col == 0) ? lin + 1 : lin - 1;
    int ssim = sel[b * NA + p];
    const float* xb_ = x + (size_t)b * CC * TT;
    float* Fb = F + (size_t)b * CC * NA;
    for (int c = 0; c < CC; ++c) {
        const float* xr = xb_ + (size_t)c * TT;
        float xa = xr[lin], xs = xr[ssim], xp = xr[spa];
        float ms = (xa + xs) * 0.5f;
        float mp = (xa + xp) * 0.5f;
        Fb[(size_t)c * NA + p] = fw0 * ms + fw1 * mp;
    }
}

// ---------------- K4b: 1x1 conv GEMM + BN + SiLU ----------------
__global__ void __launch_bounds__(256) k_conv(const float* __restrict__ F, const float* __restrict__ W,
                                              const float* __restrict__ gamma, const float* __restrict__ beta,
                                              const float* __restrict__ mean, const float* __restrict__ var,
                                              float* __restrict__ out) {
    __shared__ float Ws[16][68];
    __shared__ float Fs[16][68];
    int b = blockIdx.z;
    int o0 = blockIdx.y * 64;
    int p0 = blockIdx.x * 64;
    int tid = threadIdx.x;
    int tr = tid >> 4, tc = tid & 15;
    int sr = tid >> 2, skb = (tid & 3) * 4;
    int fkk = tid >> 4, fj = (tid & 15) * 4;
    const float* Fb = F + (size_t)b * CC * NA;
    float acc[4][4];
#pragma unroll
    for (int u = 0; u < 4; ++u)
#pragma unroll
        for (int v = 0; v < 4; ++v) acc[u][v] = 0.f;

    for (int kt = 0; kt < CC / 16; ++kt) {
        __syncthreads();
        float4 w4 = *(const float4*)(W + (size_t)(o0 + sr) * CC + kt * 16 + skb);
        Ws[skb + 0][sr] = w4.x; Ws[skb + 1][sr] = w4.y;
        Ws[skb + 2][sr] = w4.z; Ws[skb + 3][sr] = w4.w;
        float4 f4 = *(const float4*)(Fb + (size_t)(kt * 16 + fkk) * NA + p0 + fj);
        *(float4*)&Fs[fkk][fj] = f4;
        __syncthreads();
#pragma unroll
        for (int kk = 0; kk < 16; ++kk) {
            float4 av = *(const float4*)&Ws[kk][tr * 4];
            float4 bv4 = *(const float4*)&Fs[kk][tc * 4];
            float a_[4] = {av.x, av.y, av.z, av.w};
            float b_[4] = {bv4.x, bv4.y, bv4.z, bv4.w};
#pragma unroll
            for (int u = 0; u < 4; ++u)
#pragma unroll
                for (int v = 0; v < 4; ++v)
                    acc[u][v] = fmaf(a_[u], b_[v], acc[u][v]);
        }
    }
#pragma unroll
    for (int u = 0; u < 4; ++u) {
        int o = o0 + tr * 4 + u;
        float sc = gamma[o] / sqrtf(var[o] + 1e-5f);
        float sh = fmaf(-mean[o], sc, beta[o]);
        float4 r;
        float* rp = &r.x;
#pragma unroll
        for (int v = 0; v < 4; ++v) {
            float y = fmaf(acc[u][v], sc, sh);
            rp[v] = y / (1.f + expf(-y));
        }
        *(float4*)(out + ((size_t)b * OC + o) * NA + p0 + tc * 4) = r;
    }
}

extern "C" void kernel_launch(void* const* d_in, const int* in_sizes, int n_in,
                              void* d_out, int out_size, void* d_ws, size_t ws_size,
                              hipStream_t stream) {
    const float* x      = (const float*)d_in[0];
    const float* conv_w = (const float*)d_in[1];
    const float* gamma  = (const float*)d_in[2];
    const float* beta   = (const float*)d_in[3];
    const float* mean   = (const float*)d_in[4];
    const float* var    = (const float*)d_in[5];
    const float* fw     = (const float*)d_in[6];
    float* out = (float*)d_out;

    float* ws    = (float*)d_ws;
    float* norms = ws;                                     // BB*TT f
    float* Ap    = norms + (size_t)BB * TT;                // BB*NA*CC f
    float* Bp    = Ap + (size_t)BB * NA * CC;              // BB*NB*CC f
    float* Pv1   = Bp + (size_t)BB * NB * CC;              // BB*NPART*NA f
    float* Pv2   = Pv1 + (size_t)BB * NPART * NA;          // BB*NPART*NA f
    int*   Pi1   = (int*)(Pv2 + (size_t)BB * NPART * NA);  // BB*NPART*NA i
    int*   sel   = Pi1 + (size_t)BB * NPART * NA;          // BB*NA i
    int*   flags = sel + (size_t)BB * NA;                  // BB*NA i
    float* F     = Ap;                                     // reuse Ap region after fallback

    k_norm<<<BB * TT / 256, 256, 0, stream>>>(x, norms);
    k_pack<<<dim3(TT / 64, CC / 64, BB), 256, 0, stream>>>(x, norms, Ap, Bp);
    k_sim<<<dim3(NA / 128, NCH, BB), 256, 0, stream>>>(Ap, Bp, Pv1, Pi1, Pv2);
    k_reduce2<<<BB * NA / 256, 256, 0, stream>>>(Pv1, Pi1, Pv2, sel, flags);
    k_fallback<<<BB * NA, 512, 0, stream>>>(Ap, Bp, flags, sel);
    k_fuse<<<dim3(NA / 256, BB), 256, 0, stream>>>(x, sel, fw, F);
    k_conv<<<dim3(NA / 64, OC / 64, BB), 256, 0, stream>>>(F, conv_w, gamma, beta, mean, var, out);
}

// Round 12
// 376.846 us; speedup vs baseline: 2.5268x; 1.2620x over previous
//
#include <hip/hip_runtime.h>
#include <math.h>

#define BB 16
#define CC 256
#define TT 4096
#define NA 1024
#define NB 3072
#define OC 512

#define NCH 4          // j-chunks for MFMA sim kernel (768 j each)
#define NPART (NCH*2)  // partials: chunk x wc-half (race-free per-wave writes)
#define DELTA 2e-4f    // margin below which a row falls back to exact fp32 argmax

typedef float f32x4 __attribute__((ext_vector_type(4)));
typedef short bf16x8 __attribute__((ext_vector_type(8)));

// ---------------- K1: per-token L2 norm over C ----------------
__global__ void k_norm(const float* __restrict__ x, float* __restrict__ norms) {
    int idx = blockIdx.x * 256 + threadIdx.x;   // b*TT + t
    int b = idx >> 12;
    int t = idx & 4095;
    const float* xp = x + (size_t)b * CC * TT + t;
    float s = 0.f;
#pragma unroll 8
    for (int c = 0; c < CC; ++c) {
        float v = xp[(size_t)c * TT];
        s = fmaf(v, v, s);
    }
    norms[idx] = sqrtf(s);
}

// ---------------- K2: transpose-pack normalized a/b tokens (fp32 only) ----------------
__global__ void k_pack(const float* __restrict__ x, const float* __restrict__ norms,
                       float* __restrict__ Ap, float* __restrict__ Bp) {
    __shared__ float tile[64][65];
    __shared__ float ns[64];
    int b = blockIdx.z, c0 = blockIdx.y * 64, t0 = blockIdx.x * 64;
    int tid = threadIdx.x;
#pragma unroll
    for (int rep = 0; rep < 16; ++rep) {
        int lin = rep * 256 + tid;
        int i = lin >> 6, j = lin & 63;
        tile[i][j] = x[((size_t)b * CC + c0 + i) * TT + t0 + j];
    }
    if (tid < 64) ns[tid] = norms[b * TT + t0 + tid];
    __syncthreads();
#pragma unroll
    for (int rep = 0; rep < 16; ++rep) {
        int lin = rep * 256 + tid;
        int j = lin >> 6, i = lin & 63;
        int t = t0 + j;
        float v = tile[i][j] / ns[j];
        if ((t & 3) == 0) {
            Ap[((size_t)b * NA + (t >> 2)) * CC + c0 + i] = v;
        } else {
            int g = t >> 2, r = t & 3;
            Bp[((size_t)b * NB + 3 * g + (r - 1)) * CC + c0 + i] = v;
        }
    }
}

// ---------------- K3: MFMA sim via in-register bf16 hi/lo split ----------------
__device__ inline void gl16f(const float* g, char* l) {
    __builtin_amdgcn_global_load_lds((const __attribute__((address_space(1))) void*)g,
                                     (__attribute__((address_space(3))) void*)l, 16, 0, 0);
}

__device__ inline void split8(float4 p0, float4 p1, bf16x8& hi, bf16x8& lo) {
    float f[8] = {p0.x, p0.y, p0.z, p0.w, p1.x, p1.y, p1.z, p1.w};
#pragma unroll
    for (int j = 0; j < 8; ++j) {
        uint u = __float_as_uint(f[j]);
        hi[j] = (short)(u >> 16);
        float hf = __uint_as_float(u & 0xffff0000u);
        lo[j] = (short)(__float_as_uint(f[j] - hf) >> 16);
    }
}

__global__ void __launch_bounds__(256, 2) k_sim(const float* __restrict__ Ap,
                                                const float* __restrict__ Bp,
                                                float* __restrict__ Pv1, int* __restrict__ Pi1,
                                                float* __restrict__ Pv2) {
    __shared__ __align__(16) char lds[65536];   // A-tile 32KB (128r x 64k fp32) | B-tile 32KB
    const int b = blockIdx.z;
    const int ch = blockIdx.y;
    const int i0 = blockIdx.x * 128;
    const int tid = threadIdx.x;
    const int l = tid & 63, wid = tid >> 6;
    const int wr = wid >> 1, wc = wid & 1;      // 2x2 wave grid, 64x64 per wave
    const int lr = l & 15, lk = l >> 4;
    const float* Abase = Ap + ((size_t)b * NA + i0) * CC;
    const float* Bbase = Bp + (size_t)b * NB * CC;

    float rv1[16], rv2[16];
    int ri1[16];
#pragma unroll
    for (int q = 0; q < 16; ++q) { rv1[q] = -1e30f; rv2[q] = -1e30f; ri1[q] = 0; }

    for (int jt = 0; jt < 6; ++jt) {
        const int j0 = ch * 768 + jt * 128;
        f32x4 acc[4][4];
#pragma unroll
        for (int mf = 0; mf < 4; ++mf)
#pragma unroll
            for (int nf = 0; nf < 4; ++nf) acc[mf][nf] = (f32x4){0.f, 0.f, 0.f, 0.f};

        for (int kt = 0; kt < 4; ++kt) {
            __syncthreads();
            // stage fp32 tiles; source pre-swizzled at 16B granularity: slot' = slot ^ (r&14)
#pragma unroll
            for (int s = 0; s < 8; ++s) {
                int off = s * 4096 + tid * 16;
                int r = off >> 8;
                int slot = (off >> 4) & 15;
                int srco = kt * 64 + ((slot ^ (r & 14)) << 2);
                gl16f(Abase + (size_t)r * CC + srco, lds + off);
                gl16f(Bbase + (size_t)(j0 + r) * CC + srco, lds + 32768 + off);
            }
            __syncthreads();
#pragma unroll
            for (int ks = 0; ks < 2; ++ks) {
                bf16x8 ahi[4], alo[4];
#pragma unroll
                for (int mf = 0; mf < 4; ++mf) {
                    int r = wr * 64 + mf * 16 + lr;
                    int sl = ((ks * 4 + lk) * 2) ^ (r & 14);
                    float4 p0 = *(const float4*)(lds + r * 256 + sl * 16);
                    float4 p1 = *(const float4*)(lds + r * 256 + sl * 16 + 16);
                    split8(p0, p1, ahi[mf], alo[mf]);
                }
#pragma unroll
                for (int nf = 0; nf < 4; ++nf) {
                    int r = wc * 64 + nf * 16 + lr;
                    int sl = ((ks * 4 + lk) * 2) ^ (r & 14);
                    float4 p0 = *(const float4*)(lds + 32768 + r * 256 + sl * 16);
                    float4 p1 = *(const float4*)(lds + 32768 + r * 256 + sl * 16 + 16);
                    bf16x8 bhi, blo;
                    split8(p0, p1, bhi, blo);
#pragma unroll
                    for (int mf = 0; mf < 4; ++mf) {
                        acc[mf][nf] = __builtin_amdgcn_mfma_f32_16x16x32_bf16(ahi[mf], blo, acc[mf][nf], 0, 0, 0);
                        acc[mf][nf] = __builtin_amdgcn_mfma_f32_16x16x32_bf16(alo[mf], bhi, acc[mf][nf], 0, 0, 0);
                        acc[mf][nf] = __builtin_amdgcn_mfma_f32_16x16x32_bf16(ahi[mf], bhi, acc[mf][nf], 0, 0, 0);
                    }
                }
            }
        }
        // per-row top2: D mapping col=lane&15, row=(lane>>4)*4+reg  [m89]
#pragma unroll
        for (int mf = 0; mf < 4; ++mf)
#pragma unroll
            for (int reg = 0; reg < 4; ++reg) {
                int q = mf * 4 + reg;
                float v1 = acc[mf][0][reg];
                int i1 = j0 + wc * 64 + lr;
                float v2 = -1e30f;
#pragma unroll
                for (int nf = 1; nf < 4; ++nf) {
                    float xv = acc[mf][nf][reg];
                    int xi = j0 + wc * 64 + nf * 16 + lr;
                    if (xv > v1) { v2 = v1; v1 = xv; i1 = xi; }
                    else v2 = fmaxf(v2, xv);
                }
#pragma unroll
                for (int d = 1; d < 16; d <<= 1) {
                    float ov1 = __shfl_xor(v1, d, 64);
                    int oi1 = __shfl_xor(i1, d, 64);
                    float ov2 = __shfl_xor(v2, d, 64);
                    bool take = (ov1 > v1) || (ov1 == v1 && oi1 < i1);
                    float bw = take ? v1 : ov1;
                    v2 = fmaxf(fmaxf(v2, ov2), bw);
                    if (take) { v1 = ov1; i1 = oi1; }
                }
                bool t2 = (v1 > rv1[q]);
                float bw2 = t2 ? rv1[q] : v1;
                rv2[q] = fmaxf(fmaxf(rv2[q], v2), bw2);
                if (t2) { rv1[q] = v1; ri1[q] = i1; }
            }
    }
    // race-free: each wave writes its own (chunk, wc-half) partial
    if (lr == 0) {
        int pch = ch * 2 + wc;
#pragma unroll
        for (int mf = 0; mf < 4; ++mf)
#pragma unroll
            for (int reg = 0; reg < 4; ++reg) {
                int row = i0 + wr * 64 + mf * 16 + lk * 4 + reg;
                size_t o = ((size_t)b * NPART + pch) * NA + row;
                int q = mf * 4 + reg;
                Pv1[o] = rv1[q]; Pi1[o] = ri1[q]; Pv2[o] = rv2[q];
            }
    }
}

// ---------------- K3z: reset worklist count ----------------
__global__ void k_zero(int* __restrict__ count) {
    if (threadIdx.x == 0 && blockIdx.x == 0) *count = 0;
}

// ---------------- K3b: merge partials -> sel + compact flagged worklist ----------------
__global__ void k_reduce2(const float* __restrict__ Pv1, const int* __restrict__ Pi1,
                          const float* __restrict__ Pv2, int* __restrict__ sel,
                          int* __restrict__ wl, int* __restrict__ count) {
    int idx = blockIdx.x * 256 + threadIdx.x;   // b*NA + a
    int b = idx >> 10;
    int a = idx & 1023;
    float v1 = -1e30f, v2 = -1e30f;
    int i1 = 0x7fffffff;
#pragma unroll
    for (int pc = 0; pc < NPART; ++pc) {
        size_t o = ((size_t)b * NPART + pc) * NA + a;
        float nv1 = Pv1[o];
        int ni1 = Pi1[o];
        bool take = (nv1 > v1) || (nv1 == v1 && ni1 < i1);
        float bw = take ? v1 : nv1;
        v2 = fmaxf(fmaxf(v2, Pv2[o]), bw);
        if (take) { v1 = nv1; i1 = ni1; }
    }
    int g = i1 / 3, r = i1 - 3 * g;
    sel[idx] = 4 * g + r + 1;
    if (v1 - v2 < DELTA) {
        int p = atomicAdd(count, 1);
        wl[p] = idx;
    }
}

// ---------------- K3c: exact fp32 re-argmax for flagged rows (worklist) ----------------
// Fixed grid, grid-stride over worklist. Per row: 8 waves x 4 16-lane groups;
// group handles j = w*4+grp + 32k (ascending per group-lead). Lane lg owns elems
// {q*64 + lg*4} -> per-group loads are contiguous 256B (coalesced). 4-step
// shfl reduce within group; merges use (v >, tie -> smaller j).
__global__ void __launch_bounds__(512) k_fallback(const float* __restrict__ Ap,
                                                  const float* __restrict__ Bp,
                                                  const int* __restrict__ wl,
                                                  const int* __restrict__ count,
                                                  int* __restrict__ sel) {
    int n = *count;
    __shared__ float arow[CC];
    __shared__ float wv[8];
    __shared__ int wi[8];
    int tid = threadIdx.x;                // 512 threads = 8 waves
    int l = tid & 63, w = tid >> 6;
    int lg = l & 15, grp = l >> 4;
    for (int it = blockIdx.x; it < n; it += gridDim.x) {
        int row = wl[it];
        int b = row >> 10, a = row & 1023;
        __syncthreads();                  // protect arow/wv reuse across iterations
        if (tid < 64) *(float4*)&arow[tid * 4] = *(const float4*)(Ap + ((size_t)b * NA + a) * CC + tid * 4);
        __syncthreads();
        float4 av[4];
#pragma unroll
        for (int q = 0; q < 4; ++q) av[q] = *(const float4*)&arow[q * 64 + lg * 4];
        const float* Bb = Bp + (size_t)b * NB * CC;
        float bv = -1e30f;
        int bi = 0;
        for (int j = w * 4 + grp; j < NB; j += 32) {
            const float* br = Bb + (size_t)j * CC + lg * 4;
            float s = 0.f;
#pragma unroll
            for (int q = 0; q < 4; ++q) {
                float4 bb = *(const float4*)(br + q * 64);
                s = fmaf(av[q].w, bb.w, fmaf(av[q].z, bb.z, fmaf(av[q].y, bb.y, fmaf(av[q].x, bb.x, s))));
            }
#pragma unroll
            for (int d = 1; d < 16; d <<= 1) s += __shfl_xor(s, d, 64);
            if (lg == 0 && s > bv) { bv = s; bi = j; }   // ascending per group-lead
        }
        // merge 4 group-leads within wave (non-leads hold -1e30)
#pragma unroll
        for (int d = 16; d < 64; d <<= 1) {
            float ov = __shfl_xor(bv, d, 64);
            int oi = __shfl_xor(bi, d, 64);
            if (ov > bv || (ov == bv && oi < bi)) { bv = ov; bi = oi; }
        }
        if (l == 0) { wv[w] = bv; wi[w] = bi; }
        __syncthreads();
        if (tid == 0) {
            float vm = wv[0]; int im = wi[0];
#pragma unroll
            for (int q = 1; q < 8; ++q)
                if (wv[q] > vm || (wv[q] == vm && wi[q] < im)) { vm = wv[q]; im = wi[q]; }
            int g = im / 3, r = im - 3 * g;
            sel[row] = 4 * g + r + 1;
        }
    }
}

// ---------------- K4a: fuse (sim-merge + spatial-merge), write F[b][c][p] ----------------
__global__ void k_fuse(const float* __restrict__ x, const int* __restrict__ sel,
                       const float* __restrict__ fwraw, float* __restrict__ F) {
    int b = blockIdx.y;
    int p = blockIdx.x * 256 + threadIdx.x;
    float w0 = fminf(fmaxf(fwraw[0], 0.f), 6.f);
    float w1 = fminf(fmaxf(fwraw[1], 0.f), 6.f);
    float s = w0 + w1 + 1e-8f;
    float fw0 = w0 / s, fw1 = w1 / s;
    int lin = 4 * p;
    int col = lin & 63;
    int spa = (col == 0) ? lin + 1 : lin - 1;
    int ssim = sel[b * NA + p];
    const float* xb_ = x + (size_t)b * CC * TT;
    float* Fb = F + (size_t)b * CC * NA;
    for (int c = 0; c < CC; ++c) {
        const float* xr = xb_ + (size_t)c * TT;
        float xa = xr[lin], xs = xr[ssim], xp = xr[spa];
        float ms = (xa + xs) * 0.5f;
        float mp = (xa + xp) * 0.5f;
        Fb[(size_t)c * NA + p] = fw0 * ms + fw1 * mp;
    }
}

// ---------------- K4b: 1x1 conv GEMM + BN + SiLU ----------------
__global__ void __launch_bounds__(256) k_conv(const float* __restrict__ F, const float* __restrict__ W,
                                              const float* __restrict__ gamma, const float* __restrict__ beta,
                                              const float* __restrict__ mean, const float* __restrict__ var,
                                              float* __restrict__ out) {
    __shared__ float Ws[16][68];
    __shared__ float Fs[16][68];
    int b = blockIdx.z;
    int o0 = blockIdx.y * 64;
    int p0 = blockIdx.x * 64;
    int tid = threadIdx.x;
    int tr = tid >> 4, tc = tid & 15;
    int sr = tid >> 2, skb = (tid & 3) * 4;
    int fkk = tid >> 4, fj = (tid & 15) * 4;
    const float* Fb = F + (size_t)b * CC * NA;
    float acc[4][4];
#pragma unroll
    for (int u = 0; u < 4; ++u)
#pragma unroll
        for (int v = 0; v < 4; ++v) acc[u][v] = 0.f;

    for (int kt = 0; kt < CC / 16; ++kt) {
        __syncthreads();
        float4 w4 = *(const float4*)(W + (size_t)(o0 + sr) * CC + kt * 16 + skb);
        Ws[skb + 0][sr] = w4.x; Ws[skb + 1][sr] = w4.y;
        Ws[skb + 2][sr] = w4.z; Ws[skb + 3][sr] = w4.w;
        float4 f4 = *(const float4*)(Fb + (size_t)(kt * 16 + fkk) * NA + p0 + fj);
        *(float4*)&Fs[fkk][fj] = f4;
        __syncthreads();
#pragma unroll
        for (int kk = 0; kk < 16; ++kk) {
            float4 av = *(const float4*)&Ws[kk][tr * 4];
            float4 bv4 = *(const float4*)&Fs[kk][tc * 4];
            float a_[4] = {av.x, av.y, av.z, av.w};
            float b_[4] = {bv4.x, bv4.y, bv4.z, bv4.w};
#pragma unroll
            for (int u = 0; u < 4; ++u)
#pragma unroll
                for (int v = 0; v < 4; ++v)
                    acc[u][v] = fmaf(a_[u], b_[v], acc[u][v]);
        }
    }
#pragma unroll
    for (int u = 0; u < 4; ++u) {
        int o = o0 + tr * 4 + u;
        float sc = gamma[o] / sqrtf(var[o] + 1e-5f);
        float sh = fmaf(-mean[o], sc, beta[o]);
        float4 r;
        float* rp = &r.x;
#pragma unroll
        for (int v = 0; v < 4; ++v) {
            float y = fmaf(acc[u][v], sc, sh);
            rp[v] = y / (1.f + expf(-y));
        }
        *(float4*)(out + ((size_t)b * OC + o) * NA + p0 + tc * 4) = r;
    }
}

extern "C" void kernel_launch(void* const* d_in, const int* in_sizes, int n_in,
                              void* d_out, int out_size, void* d_ws, size_t ws_size,
                              hipStream_t stream) {
    const float* x      = (const float*)d_in[0];
    const float* conv_w = (const float*)d_in[1];
    const float* gamma  = (const float*)d_in[2];
    const float* beta   = (const float*)d_in[3];
    const float* mean   = (const float*)d_in[4];
    const float* var    = (const float*)d_in[5];
    const float* fw     = (const float*)d_in[6];
    float* out = (float*)d_out;

    float* ws    = (float*)d_ws;
    float* norms = ws;                                     // BB*TT f
    float* Ap    = norms + (size_t)BB * TT;                // BB*NA*CC f
    float* Bp    = Ap + (size_t)BB * NA * CC;              // BB*NB*CC f
    float* Pv1   = Bp + (size_t)BB * NB * CC;              // BB*NPART*NA f
    float* Pv2   = Pv1 + (size_t)BB * NPART * NA;          // BB*NPART*NA f
    int*   Pi1   = (int*)(Pv2 + (size_t)BB * NPART * NA);  // BB*NPART*NA i
    int*   sel   = Pi1 + (size_t)BB * NPART * NA;          // BB*NA i
    int*   wl    = sel + (size_t)BB * NA;                  // BB*NA i
    int*   count = wl + (size_t)BB * NA;                   // 1 i
    float* F     = Ap;                                     // reuse Ap region after fallback

    k_norm<<<BB * TT / 256, 256, 0, stream>>>(x, norms);
    k_pack<<<dim3(TT / 64, CC / 64, BB), 256, 0, stream>>>(x, norms, Ap, Bp);
    k_sim<<<dim3(NA / 128, NCH, BB), 256, 0, stream>>>(Ap, Bp, Pv1, Pi1, Pv2);
    k_zero<<<1, 1, 0, stream>>>(count);
    k_reduce2<<<BB * NA / 256, 256, 0, stream>>>(Pv1, Pi1, Pv2, sel, wl, count);
    k_fallback<<<2048, 512, 0, stream>>>(Ap, Bp, wl, count, sel);
    k_fuse<<<dim3(NA / 256, BB), 256, 0, stream>>>(x, sel, fw, F);
    k_conv<<<dim3(NA / 64, OC / 64, BB), 256, 0, stream>>>(F, conv_w, gamma, beta, mean, var, out);
}